// Round 6
// baseline (428.622 us; speedup 1.0000x reference)
//
#include <hip/hip_runtime.h>

#define N_TOK  1024
#define D_DIM  1024
#define M_FFN  4096

typedef float f32x4 __attribute__((ext_vector_type(4)));

__device__ __forceinline__ float wave_reduce(float v) {
    #pragma unroll
    for (int off = 32; off > 0; off >>= 1) v += __shfl_xor(v, off);
    return v;
}

// ---------------- LayerNorm over 1024-elem rows, f32 -> f32 ---------------
__global__ void ln_kernel(const float* __restrict__ X,
                          const float* __restrict__ gam,
                          const float* __restrict__ bet,
                          float* __restrict__ Y) {
    int b = blockIdx.x, t = threadIdx.x;           // 256 threads, 4 elems each
    float4 x = ((const float4*)(X + (size_t)b * N_TOK))[t];
    float s = x.x + x.y + x.z + x.w;
    float q = x.x*x.x + x.y*x.y + x.z*x.z + x.w*x.w;
    s = wave_reduce(s); q = wave_reduce(q);
    __shared__ float sa[4], sb[4];
    int wid = t >> 6;
    if ((t & 63) == 0) { sa[wid] = s; sb[wid] = q; }
    __syncthreads();
    float ts = sa[0] + sa[1] + sa[2] + sa[3];
    float tq = sb[0] + sb[1] + sb[2] + sb[3];
    float mean = ts * (1.f / N_TOK);
    float var  = tq * (1.f / N_TOK) - mean * mean;
    float rs = rsqrtf(var + 1e-5f);
    float4 g4 = ((const float4*)gam)[t];
    float4 b4 = ((const float4*)bet)[t];
    float4 o;
    o.x = (x.x - mean) * rs * g4.x + b4.x;
    o.y = (x.y - mean) * rs * g4.y + b4.y;
    o.z = (x.z - mean) * rs * g4.z + b4.z;
    o.w = (x.w - mean) * rs * g4.w + b4.w;
    ((float4*)(Y + (size_t)b * N_TOK))[t] = o;
}

// ---- C(32 x N) = A(32 x K) @ W(N x K)^T, lanes span K (coalesced W) ------
// W stream is register double-buffered (prefetch next chunk before FMAs)
// and nontemporal. Distinct kernel names per call site for attribution.
__device__ __forceinline__ void gemm_body(const float* __restrict__ A,
                                          const float* __restrict__ W,
                                          float* __restrict__ C,
                                          const float* __restrict__ bias,
                                          int N, int K, int kchunk, int mode,
                                          int bx, int by) {
    int t = threadIdx.x;
    int lane = t & 63, wid = t >> 6;
    int ksub = lane & 15, nsub = lane >> 4;
    int mhalf = wid & 1, ngrp = wid >> 1;
    int n = bx * 8 + ngrp * 4 + nsub;
    int k0 = by * kchunk + ksub * 4;
    const float* wp = W + (size_t)n * K + k0;
    const float* ap = A + (size_t)mhalf * 16 * K + k0;
    float acc[16];
    #pragma unroll
    for (int j = 0; j < 16; j++) acc[j] = 0.f;
    f32x4 w4 = __builtin_nontemporal_load((const f32x4*)wp);
    for (int kk = 0; kk < kchunk; kk += 64) {
        f32x4 wn;
        if (kk + 64 < kchunk)
            wn = __builtin_nontemporal_load((const f32x4*)(wp + kk + 64));
        #pragma unroll
        for (int j = 0; j < 16; j++) {
            float4 a4 = *(const float4*)(ap + (size_t)j * K + kk);
            acc[j] += a4.x*w4.x + a4.y*w4.y + a4.z*w4.z + a4.w*w4.w;
        }
        w4 = wn;
    }
    #pragma unroll
    for (int j = 0; j < 16; j++) {
        #pragma unroll
        for (int off = 1; off < 16; off <<= 1)
            acc[j] += __shfl_xor(acc[j], off);
    }
    if (ksub == 0) {
        int mbase = mhalf * 16;
        if (mode == 2) {
            #pragma unroll
            for (int j = 0; j < 16; j++)
                atomicAdd(C + (size_t)(mbase + j) * N + n, acc[j]);
        } else if (mode == 1) {
            float bn = bias[n];
            #pragma unroll
            for (int j = 0; j < 16; j++) {
                float z = acc[j] + bn;
                C[(size_t)(mbase + j) * N + n] = z / (1.f + __expf(-z));
            }
        } else {
            #pragma unroll
            for (int j = 0; j < 16; j++)
                C[(size_t)(mbase + j) * N + n] = acc[j];
        }
    }
}

// mu/sigma GEMM: grid (128, 1, 2); z selects weight/output pair
__global__ void gemm_mu_sigma(const float* __restrict__ A,
                              const float* __restrict__ W0,
                              const float* __restrict__ W1,
                              float* __restrict__ C0,
                              float* __restrict__ C1) {
    const float* W = blockIdx.z ? W1 : W0;
    float*       C = blockIdx.z ? C1 : C0;
    gemm_body(A, W, C, nullptr, 1024, 1024, 1024, 0, blockIdx.x, 0);
}

// ffn1 GEMM: grid (512); fused bias+silu epilogue
__global__ void gemm_ffn1(const float* __restrict__ A,
                          const float* __restrict__ W,
                          float* __restrict__ C,
                          const float* __restrict__ bias) {
    gemm_body(A, W, C, bias, 4096, 1024, 1024, 1, blockIdx.x, 0);
}

// ffn2 GEMM: grid (128, 2); split-K atomics into zeroed accumulator
__global__ void gemm_ffn2(const float* __restrict__ A,
                          const float* __restrict__ W,
                          float* __restrict__ C) {
    gemm_body(A, W, C, nullptr, 1024, 4096, 2048, 2, blockIdx.x, blockIdx.y);
}

// ------------- Gaussian-kernel attention row sweep (the big one) ----------
// One WAVE per row: 64 lanes x 16 elems; 8 nontemporal 16B loads in flight
// per lane, shuffle-reduce only — no LDS, no __syncthreads.
__global__ void attn_kernel(const float* __restrict__ Kp,
                            const float* __restrict__ Vp,
                            const float* __restrict__ Qp,
                            const float* __restrict__ mu_acc,
                            const float* __restrict__ sg_acc,
                            const float* __restrict__ mu_b,
                            const float* __restrict__ sg_b,
                            float* __restrict__ xo) {
    int t = threadIdx.x;
    int lane = t & 63, wid = t >> 6;
    int row = blockIdx.x * 4 + wid;      // grid 8192, 4 rows/block
    const f32x4* kp = (const f32x4*)(Kp + (size_t)row * D_DIM);
    const f32x4* vp = (const f32x4*)(Vp + (size_t)row * D_DIM);
    f32x4 k4[4], v4[4];
    #pragma unroll
    for (int c = 0; c < 4; c++) k4[c] = __builtin_nontemporal_load(kp + c * 64 + lane);
    #pragma unroll
    for (int c = 0; c < 4; c++) v4[c] = __builtin_nontemporal_load(vp + c * 64 + lane);
    int i = row & (N_TOK - 1);
    float mu = tanhf(mu_acc[row] + mu_b[i]);
    float sg = sg_acc[row] + sg_b[i];
    float coef = -0.5f / (sg * sg + 1e-8f);
    float acc = 0.f;
    #pragma unroll
    for (int c = 0; c < 4; c++) {
        float d;
        d = k4[c].x - mu; acc += __expf(coef * d * d) * v4[c].x;
        d = k4[c].y - mu; acc += __expf(coef * d * d) * v4[c].y;
        d = k4[c].z - mu; acc += __expf(coef * d * d) * v4[c].z;
        d = k4[c].w - mu; acc += __expf(coef * d * d) * v4[c].w;
    }
    acc = wave_reduce(acc);
    if (lane == 0) xo[row] = acc + Qp[row];
}

// --------------------- out = x + acc2 + b2, f32 ---------------------------
__global__ void final_kernel(const float* __restrict__ x,
                             const float* __restrict__ acc2,
                             const float* __restrict__ b2,
                             float* __restrict__ out) {
    int idx = blockIdx.x * 256 + threadIdx.x;    // 32768 total
    out[idx] = x[idx] + acc2[idx] + b2[idx & (N_TOK - 1)];
}

extern "C" void kernel_launch(void* const* d_in, const int* in_sizes, int n_in,
                              void* d_out, int out_size, void* d_ws, size_t ws_size,
                              hipStream_t stream) {
    const float* Q       = (const float*)d_in[0];
    const float* Kp      = (const float*)d_in[1];
    const float* Vp      = (const float*)d_in[2];
    const float* mu_w    = (const float*)d_in[3];
    const float* mu_b    = (const float*)d_in[4];
    const float* sigma_w = (const float*)d_in[5];
    const float* sigma_b = (const float*)d_in[6];
    const float* w1      = (const float*)d_in[7];
    const float* b1      = (const float*)d_in[8];
    const float* w2      = (const float*)d_in[9];
    const float* b2      = (const float*)d_in[10];
    const float* ln_ff_g = (const float*)d_in[11];
    const float* ln_ff_b = (const float*)d_in[12];
    const float* ln_q_g  = (const float*)d_in[13];
    const float* ln_q_b  = (const float*)d_in[14];

    // Workspace layout (all fp32), ~1.3 MB total
    float* mu_acc = (float*)d_ws;                  // 32768
    float* sg_acc = mu_acc + 32768;                // 32768
    float* f2_acc = sg_acc + 32768;                // 32768 (atomic accum)
    float* xbuf   = f2_acc + 32768;                // 32768
    float* qln    = xbuf   + 32768;                // 32768
    float* h0     = qln    + 32768;                // 32768
    float* g      = h0     + 32768;                // 131072

    // zero only the split-K accumulator for ffn2
    hipMemsetAsync(f2_acc, 0, (size_t)32768 * sizeof(float), stream);

    // 1) q = LN(Q)
    ln_kernel<<<32, 256, 0, stream>>>(Q, ln_q_g, ln_q_b, qln);

    // 2) mu_acc = q @ mu_w^T ; sg_acc = q @ sigma_w^T
    gemm_mu_sigma<<<dim3(128, 1, 2), 256, 0, stream>>>(
        qln, mu_w, sigma_w, mu_acc, sg_acc);

    // 3) x = sum_d exp(-0.5(K-mu)^2/(sigma^2+1e-8)) * V + Q
    attn_kernel<<<8192, 256, 0, stream>>>(Kp, Vp, Q, mu_acc, sg_acc,
                                          mu_b, sigma_b, xbuf);

    // 4) h0 = LN(x)
    ln_kernel<<<32, 256, 0, stream>>>(xbuf, ln_ff_b == ln_ff_g ? ln_ff_g : ln_ff_g, ln_ff_b, h0);

    // 5) g = silu(h0 @ w1^T + b1)   (bias+silu fused in epilogue)
    gemm_ffn1<<<512, 256, 0, stream>>>(h0, w1, g, b1);

    // 6) f2_acc = g @ w2^T  (split-K x2, atomics) ; out = x + f2_acc + b2
    gemm_ffn2<<<dim3(128, 2), 256, 0, stream>>>(g, w2, f2_acc);
    final_kernel<<<128, 256, 0, stream>>>(xbuf, f2_acc, b2, (float*)d_out);
}

// Round 7
// 372.791 us; speedup vs baseline: 1.1498x; 1.1498x over previous
//
#include <hip/hip_runtime.h>

#define N_TOK  1024
#define D_DIM  1024
#define M_FFN  4096

typedef float f32x4 __attribute__((ext_vector_type(4)));

__device__ __forceinline__ float wave_reduce(float v) {
    #pragma unroll
    for (int off = 32; off > 0; off >>= 1) v += __shfl_xor(v, off);
    return v;
}

// ---------------- LayerNorm over 1024-elem rows, f32 -> f32 ---------------
__global__ void ln_kernel(const float* __restrict__ X,
                          const float* __restrict__ gam,
                          const float* __restrict__ bet,
                          float* __restrict__ Y) {
    int b = blockIdx.x, t = threadIdx.x;           // 256 threads, 4 elems each
    float4 x = ((const float4*)(X + (size_t)b * N_TOK))[t];
    float s = x.x + x.y + x.z + x.w;
    float q = x.x*x.x + x.y*x.y + x.z*x.z + x.w*x.w;
    s = wave_reduce(s); q = wave_reduce(q);
    __shared__ float sa[4], sb[4];
    int wid = t >> 6;
    if ((t & 63) == 0) { sa[wid] = s; sb[wid] = q; }
    __syncthreads();
    float ts = sa[0] + sa[1] + sa[2] + sa[3];
    float tq = sb[0] + sb[1] + sb[2] + sb[3];
    float mean = ts * (1.f / N_TOK);
    float var  = tq * (1.f / N_TOK) - mean * mean;
    float rs = rsqrtf(var + 1e-5f);
    float4 g4 = ((const float4*)gam)[t];
    float4 b4 = ((const float4*)bet)[t];
    float4 o;
    o.x = (x.x - mean) * rs * g4.x + b4.x;
    o.y = (x.y - mean) * rs * g4.y + b4.y;
    o.z = (x.z - mean) * rs * g4.z + b4.z;
    o.w = (x.w - mean) * rs * g4.w + b4.w;
    ((float4*)(Y + (size_t)b * N_TOK))[t] = o;
}

// ---- C(32 x N) = A(32 x K) @ W(N x K)^T, lanes span K (coalesced W) ------
// R5-form inner loop (no explicit prefetch — it regressed in R6).
__device__ __forceinline__ void gemm_body(const float* __restrict__ A,
                                          const float* __restrict__ W,
                                          float* __restrict__ C,
                                          const float* __restrict__ bias,
                                          int N, int K, int kchunk, int mode,
                                          int bx, int by) {
    int t = threadIdx.x;
    int lane = t & 63, wid = t >> 6;
    int ksub = lane & 15, nsub = lane >> 4;
    int mhalf = wid & 1, ngrp = wid >> 1;
    int n = bx * 8 + ngrp * 4 + nsub;
    int k0 = by * kchunk + ksub * 4;
    const float* wp = W + (size_t)n * K + k0;
    const float* ap = A + (size_t)mhalf * 16 * K + k0;
    float acc[16];
    #pragma unroll
    for (int j = 0; j < 16; j++) acc[j] = 0.f;
    for (int kk = 0; kk < kchunk; kk += 64) {
        f32x4 w4 = __builtin_nontemporal_load((const f32x4*)(wp + kk));
        #pragma unroll
        for (int j = 0; j < 16; j++) {
            float4 a4 = *(const float4*)(ap + (size_t)j * K + kk);
            acc[j] += a4.x*w4.x + a4.y*w4.y + a4.z*w4.z + a4.w*w4.w;
        }
    }
    #pragma unroll
    for (int j = 0; j < 16; j++) {
        #pragma unroll
        for (int off = 1; off < 16; off <<= 1)
            acc[j] += __shfl_xor(acc[j], off);
    }
    if (ksub == 0) {
        int mbase = mhalf * 16;
        if (mode == 2) {
            #pragma unroll
            for (int j = 0; j < 16; j++)
                atomicAdd(C + (size_t)(mbase + j) * N + n, acc[j]);
        } else if (mode == 1) {
            float bn = bias[n];
            #pragma unroll
            for (int j = 0; j < 16; j++) {
                float z = acc[j] + bn;
                C[(size_t)(mbase + j) * N + n] = z / (1.f + __expf(-z));
            }
        } else {
            #pragma unroll
            for (int j = 0; j < 16; j++)
                C[(size_t)(mbase + j) * N + n] = acc[j];
        }
    }
}

// mu/sigma GEMM: grid (128, 2, 2); y = split-K, z selects weight/output pair
__global__ void gemm_mu_sigma(const float* __restrict__ A,
                              const float* __restrict__ W0,
                              const float* __restrict__ W1,
                              float* __restrict__ C0,
                              float* __restrict__ C1) {
    const float* W = blockIdx.z ? W1 : W0;
    float*       C = blockIdx.z ? C1 : C0;
    gemm_body(A, W, C, nullptr, 1024, 1024, 512, 2, blockIdx.x, blockIdx.y);
}

// ffn1 GEMM: grid (512); fused bias+silu epilogue
__global__ void gemm_ffn1(const float* __restrict__ A,
                          const float* __restrict__ W,
                          float* __restrict__ C,
                          const float* __restrict__ bias) {
    gemm_body(A, W, C, bias, 4096, 1024, 1024, 1, blockIdx.x, 0);
}

// ffn2 GEMM: grid (128, 4); split-K atomics into zeroed accumulator
__global__ void gemm_ffn2(const float* __restrict__ A,
                          const float* __restrict__ W,
                          float* __restrict__ C) {
    gemm_body(A, W, C, nullptr, 1024, 4096, 1024, 2, blockIdx.x, blockIdx.y);
}

// ------------- Gaussian-kernel attention row sweep (the big one) ----------
// TWO rows per wave: 16 nt loads (8K+8V) in flight per lane, shuffle-reduce
// only — no LDS, no __syncthreads. Grid 4096 x 256 (4 waves = 8 rows/block).
__global__ void attn_kernel(const float* __restrict__ Kp,
                            const float* __restrict__ Vp,
                            const float* __restrict__ Qp,
                            const float* __restrict__ mu_acc,
                            const float* __restrict__ sg_acc,
                            const float* __restrict__ mu_b,
                            const float* __restrict__ sg_b,
                            float* __restrict__ xo) {
    int t = threadIdx.x;
    int lane = t & 63, wid = t >> 6;
    int row0 = blockIdx.x * 8 + wid * 2;
    int row1 = row0 + 1;
    const f32x4* kp0 = (const f32x4*)(Kp + (size_t)row0 * D_DIM);
    const f32x4* vp0 = (const f32x4*)(Vp + (size_t)row0 * D_DIM);
    const f32x4* kp1 = (const f32x4*)(Kp + (size_t)row1 * D_DIM);
    const f32x4* vp1 = (const f32x4*)(Vp + (size_t)row1 * D_DIM);
    f32x4 ka[4], va[4], kb[4], vb[4];
    #pragma unroll
    for (int c = 0; c < 4; c++) ka[c] = __builtin_nontemporal_load(kp0 + c * 64 + lane);
    #pragma unroll
    for (int c = 0; c < 4; c++) kb[c] = __builtin_nontemporal_load(kp1 + c * 64 + lane);
    #pragma unroll
    for (int c = 0; c < 4; c++) va[c] = __builtin_nontemporal_load(vp0 + c * 64 + lane);
    #pragma unroll
    for (int c = 0; c < 4; c++) vb[c] = __builtin_nontemporal_load(vp1 + c * 64 + lane);
    int i0 = row0 & (N_TOK - 1), i1 = row1 & (N_TOK - 1);
    float mu0 = tanhf(mu_acc[row0] + mu_b[i0]);
    float mu1 = tanhf(mu_acc[row1] + mu_b[i1]);
    float sg0 = sg_acc[row0] + sg_b[i0];
    float sg1 = sg_acc[row1] + sg_b[i1];
    float c0 = -0.5f / (sg0 * sg0 + 1e-8f);
    float c1 = -0.5f / (sg1 * sg1 + 1e-8f);
    float acc0 = 0.f, acc1 = 0.f, d;
    #pragma unroll
    for (int c = 0; c < 4; c++) {
        d = ka[c].x - mu0; acc0 += __expf(c0 * d * d) * va[c].x;
        d = ka[c].y - mu0; acc0 += __expf(c0 * d * d) * va[c].y;
        d = ka[c].z - mu0; acc0 += __expf(c0 * d * d) * va[c].z;
        d = ka[c].w - mu0; acc0 += __expf(c0 * d * d) * va[c].w;
        d = kb[c].x - mu1; acc1 += __expf(c1 * d * d) * vb[c].x;
        d = kb[c].y - mu1; acc1 += __expf(c1 * d * d) * vb[c].y;
        d = kb[c].z - mu1; acc1 += __expf(c1 * d * d) * vb[c].z;
        d = kb[c].w - mu1; acc1 += __expf(c1 * d * d) * vb[c].w;
    }
    acc0 = wave_reduce(acc0);
    acc1 = wave_reduce(acc1);
    if (lane == 0) {
        xo[row0] = acc0 + Qp[row0];
        xo[row1] = acc1 + Qp[row1];
    }
}

// --------------------- out = x + acc2 + b2, f32 ---------------------------
__global__ void final_kernel(const float* __restrict__ x,
                             const float* __restrict__ acc2,
                             const float* __restrict__ b2,
                             float* __restrict__ out) {
    int idx = blockIdx.x * 256 + threadIdx.x;    // 32768 total
    out[idx] = x[idx] + acc2[idx] + b2[idx & (N_TOK - 1)];
}

extern "C" void kernel_launch(void* const* d_in, const int* in_sizes, int n_in,
                              void* d_out, int out_size, void* d_ws, size_t ws_size,
                              hipStream_t stream) {
    const float* Q       = (const float*)d_in[0];
    const float* Kp      = (const float*)d_in[1];
    const float* Vp      = (const float*)d_in[2];
    const float* mu_w    = (const float*)d_in[3];
    const float* mu_b    = (const float*)d_in[4];
    const float* sigma_w = (const float*)d_in[5];
    const float* sigma_b = (const float*)d_in[6];
    const float* w1      = (const float*)d_in[7];
    const float* b1      = (const float*)d_in[8];
    const float* w2      = (const float*)d_in[9];
    const float* b2      = (const float*)d_in[10];
    const float* ln_ff_g = (const float*)d_in[11];
    const float* ln_ff_b = (const float*)d_in[12];
    const float* ln_q_g  = (const float*)d_in[13];
    const float* ln_q_b  = (const float*)d_in[14];

    // Workspace layout (all fp32). mu/sg/f2 contiguous -> single memset.
    float* mu_acc = (float*)d_ws;                  // 32768 (atomic accum)
    float* sg_acc = mu_acc + 32768;                // 32768 (atomic accum)
    float* f2_acc = sg_acc + 32768;                // 32768 (atomic accum)
    float* xbuf   = f2_acc + 32768;                // 32768
    float* qln    = xbuf   + 32768;                // 32768
    float* h0     = qln    + 32768;                // 32768
    float* g      = h0     + 32768;                // 131072

    // zero all three split-K accumulators in one 384 KB fill
    hipMemsetAsync(mu_acc, 0, (size_t)98304 * sizeof(float), stream);

    // 1) q = LN(Q)
    ln_kernel<<<32, 256, 0, stream>>>(Q, ln_q_g, ln_q_b, qln);

    // 2) mu_acc = q @ mu_w^T ; sg_acc = q @ sigma_w^T  (split-K x2, atomics)
    gemm_mu_sigma<<<dim3(128, 2, 2), 256, 0, stream>>>(
        qln, mu_w, sigma_w, mu_acc, sg_acc);

    // 3) x = sum_d exp(-0.5(K-mu)^2/(sigma^2+1e-8)) * V + Q
    attn_kernel<<<4096, 256, 0, stream>>>(Kp, Vp, Q, mu_acc, sg_acc,
                                          mu_b, sigma_b, xbuf);

    // 4) h0 = LN(x)
    ln_kernel<<<32, 256, 0, stream>>>(xbuf, ln_ff_g, ln_ff_b, h0);

    // 5) g = silu(h0 @ w1^T + b1)   (bias+silu fused in epilogue)
    gemm_ffn1<<<512, 256, 0, stream>>>(h0, w1, g, b1);

    // 6) f2_acc = g @ w2^T  (split-K x4, atomics) ; out = x + f2_acc + b2
    gemm_ffn2<<<dim3(128, 4), 256, 0, stream>>>(g, w2, f2_acc);
    final_kernel<<<128, 256, 0, stream>>>(xbuf, f2_acc, b2, (float*)d_out);
}